// Round 2
// baseline (47.972 us; speedup 1.0000x reference)
//
#include <hip/hip_runtime.h>

#define LOG2E 1.4426950408889634f
#define C1 (10.0f * LOG2E)

// Prep kernel.
// Blocks 0..53: derive params. Input layout [co][ci][nb][kh][kw] (flat 13824),
//   output layout [co][ci][kh][kw][nb] float4 {Ec, T1=exp2(C1*Ec), Zk=2*LOG2E*k, W2=2*Ps*coef}
// Blocks 54..61: K0[co] = out_bias[co] + sum_{432} coef*(Ps+bias); 4 waves/block, 1 co each.
__global__ __launch_bounds__(256) void prep_kernel(
    const float* __restrict__ kk, const float* __restrict__ Ec,
    const float* __restrict__ Ps, const float* __restrict__ bias,
    const float* __restrict__ coef, const float* __restrict__ out_bias,
    float4* __restrict__ dp, float* __restrict__ K0) {
    const int bid = blockIdx.x;
    const int tid = threadIdx.x;
    if (bid < 54) {
        int i = bid * 256 + tid;            // 54*256 = 13824 exactly
        int co = i / 432;
        int r  = i - co * 432;              // [ci][nb][kh][kw]
        int ci = r / 27;
        int r2 = r - ci * 27;
        int nb = r2 / 9;
        int r3 = r2 - nb * 9;               // kh*3+kw
        int o  = ((co * 16 + ci) * 9 + r3) * 3 + nb;
        float e = Ec[i];
        dp[o] = make_float4(e, __builtin_amdgcn_exp2f(C1 * e),
                            2.0f * LOG2E * kk[i], 2.0f * Ps[i] * coef[i]);
    } else {
        int co = (bid - 54) * 4 + (tid >> 6);
        int lane = tid & 63;
        float sum = 0.f;
        for (int j = lane; j < 432; j += 64) {
            int idx = co * 432 + j;
            sum += coef[idx] * (Ps[idx] + bias[idx]);
        }
        #pragma unroll
        for (int off = 32; off >= 1; off >>= 1) sum += __shfl_down(sum, off, 64);
        if (lane == 0) K0[co] = sum + out_bias[co];
    }
}

// Main: grid 2048 = (b:4, co:32, chunk:16).  256 threads:
//   wave w (tid>>6) owns ci in [w*4, w*4+4); lane = pixel within a 2-row chunk.
//   Deterministic LDS reduce across the 4 waves.
__global__ __launch_bounds__(256) void main_kernel(
    const float* __restrict__ x, const float4* __restrict__ dp,
    const float* __restrict__ K0, float* __restrict__ out) {
    __shared__ float red[256];
    const int bid = blockIdx.x;
    const int tid = threadIdx.x;
    const int chunk = bid & 15;
    const int co    = (bid >> 4) & 31;
    const int b     = bid >> 9;
    const int px = tid & 63;
    const int w  = px & 31;
    const int h  = chunk * 2 + (px >> 5);
    const int ci_base = __builtin_amdgcn_readfirstlane((int)(tid >> 6)) * 4;

    float acc = 0.f;
    #pragma unroll
    for (int i = 0; i < 4; ++i) {
        const int ci = ci_base + i;
        const float* xc = x + ((b * 16 + ci) << 10);
        const float4* pp = dp + (co * 16 + ci) * 27;   // [kh][kw][nb]
        #pragma unroll
        for (int kh = 0; kh < 3; ++kh) {
            const int hy = h + kh - 1;
            const bool rowok = (unsigned)hy < 32u;
            const float4* pk = pp + kh * 9;
            #pragma unroll
            for (int kw = 0; kw < 3; ++kw) {
                const int wx = w + kw - 1;
                const bool ok = rowok && ((unsigned)wx < 32u);
                const float xv = ok ? xc[hy * 32 + wx] : 0.f;
                const float E1 = __builtin_amdgcn_exp2f(C1 * xv);
                #pragma unroll
                for (int nb = 0; nb < 3; ++nb) {
                    const float4 P = pk[kw * 3 + nb];
                    float t1 = __builtin_fmaf(E1, P.y, 1.0f);      // 1 + E1*T1
                    float cn = __builtin_amdgcn_rcpf(t1);
                    float g  = __builtin_fmaf(-0.2f, cn, 1.0f);    // 1 - 0.2*cn
                    float sh = __builtin_fmaf(P.x, g, xv);         // x + Ec*g
                    float e2 = __builtin_amdgcn_exp2f(P.z * sh);
                    float r2 = __builtin_amdgcn_rcpf(1.0f + e2);
                    acc = __builtin_fmaf(-P.w, r2, acc);
                }
            }
        }
    }
    red[tid] = acc;
    __syncthreads();
    if (tid < 64) {
        float r = red[tid] + red[tid + 64] + red[tid + 128] + red[tid + 192];
        int o = (((b * 32 + co) * 32 + chunk * 2) << 5) + tid;
        out[o] = r + K0[co];
    }
}

extern "C" void kernel_launch(void* const* d_in, const int* in_sizes, int n_in,
                              void* d_out, int out_size, void* d_ws, size_t ws_size,
                              hipStream_t stream) {
    const float* x        = (const float*)d_in[0];
    const float* k        = (const float*)d_in[1];
    const float* Ec       = (const float*)d_in[2];
    const float* Ps       = (const float*)d_in[3];
    const float* bias     = (const float*)d_in[4];
    const float* coef     = (const float*)d_in[5];
    const float* out_bias = (const float*)d_in[6];
    float* out = (float*)d_out;

    const int NP = 32 * 16 * 27;  // 13824
    float4* dp = (float4*)d_ws;
    float* K0  = (float*)((char*)d_ws + (size_t)NP * sizeof(float4));

    prep_kernel<<<62, 256, 0, stream>>>(k, Ec, Ps, bias, coef, out_bias, dp, K0);
    main_kernel<<<2048, 256, 0, stream>>>(x, dp, K0, out);
}

// Round 3
// 31.766 us; speedup vs baseline: 1.5102x; 1.5102x over previous
//
#include <hip/hip_runtime.h>

#define LOG2E 1.4426950408889634f
#define C1 (10.0f * LOG2E)

// ws layout: xe (73984 float2 = 591872 B) | dp (13824 float4 = 221184 B) | K0 (32 f)
// xe = padded (x, exp2(C1*x)) table, [b*16+ci][34][34], pad -> (0, 1).
// dp layout [co][ci][kh][kw][nb]: {Ec, T1=exp2(C1*Ec), Zk=2*LOG2E*k, W2=2*Ps*coef}
__global__ __launch_bounds__(256) void prep_kernel(
    const float* __restrict__ x,
    const float* __restrict__ kk, const float* __restrict__ Ec,
    const float* __restrict__ Ps, const float* __restrict__ bias,
    const float* __restrict__ coef, const float* __restrict__ out_bias,
    float2* __restrict__ xe, float4* __restrict__ dp, float* __restrict__ K0) {
    const int bid = blockIdx.x, tid = threadIdx.x;
    if (bid < 289) {                       // 289*256 = 73984 = 64*34*34
        int i = bid * 256 + tid;
        int ch = i / 1156;
        int rem = i - ch * 1156;
        int r = rem / 34;
        int c = rem - r * 34;
        float xv = 0.f;
        if ((unsigned)(r - 1) < 32u && (unsigned)(c - 1) < 32u)
            xv = x[(ch << 10) + (r - 1) * 32 + (c - 1)];
        xe[i] = make_float2(xv, __builtin_amdgcn_exp2f(C1 * xv));
    } else if (bid < 343) {                // 54*256 = 13824 params
        int i = (bid - 289) * 256 + tid;
        int co = i / 432;
        int r  = i - co * 432;             // input layout [ci][nb][kh][kw]
        int ci = r / 27;
        int r2 = r - ci * 27;
        int nb = r2 / 9;
        int r3 = r2 - nb * 9;              // kh*3+kw
        int o  = ((co * 16 + ci) * 9 + r3) * 3 + nb;
        float e = Ec[i];
        dp[o] = make_float4(e, __builtin_amdgcn_exp2f(C1 * e),
                            2.0f * LOG2E * kk[i], 2.0f * Ps[i] * coef[i]);
    } else {                               // 8 blocks x 4 waves: K0 per co
        int co = (bid - 343) * 4 + (tid >> 6);
        int lane = tid & 63;
        float sum = 0.f;
        for (int j = lane; j < 432; j += 64) {
            int idx = co * 432 + j;
            sum += coef[idx] * (Ps[idx] + bias[idx]);
        }
        #pragma unroll
        for (int off = 32; off >= 1; off >>= 1) sum += __shfl_down(sum, off, 64);
        if (lane == 0) K0[co] = sum + out_bias[co];
    }
}

// grid 2048 = (b:4, co:32, chunk:16 of 2 rows); 4 waves, wave w owns ci [4w,4w+4)
__global__ __launch_bounds__(256) void main_kernel(
    const float2* __restrict__ xe, const float4* __restrict__ dp,
    const float* __restrict__ K0, float* __restrict__ out) {
    __shared__ float red[256];
    const int bid = blockIdx.x, tid = threadIdx.x;
    const int chunk = bid & 15;
    const int co    = (bid >> 4) & 31;
    const int b     = bid >> 9;
    const int px = tid & 63;
    const int w  = px & 31;
    const int h  = chunk * 2 + (px >> 5);
    const int cb = __builtin_amdgcn_readfirstlane((int)(tid >> 6)) * 4;

    float a0 = 0.f, a1 = 0.f, a2 = 0.f;
    #pragma unroll
    for (int i = 0; i < 4; ++i) {
        const int ci = cb + i;
        const float2* xp = xe + ((b * 16 + ci) * 34 + h + 1) * 34 + (w + 1);
        const float4* pk = dp + (co * 16 + ci) * 27;
        float2 X[9];
        #pragma unroll
        for (int kh = 0; kh < 3; ++kh)
            #pragma unroll
            for (int kw = 0; kw < 3; ++kw)
                X[kh * 3 + kw] = xp[(kh - 1) * 34 + (kw - 1)];
        #pragma unroll
        for (int j = 0; j < 9; ++j) {
            const float xv = X[j].x, E1 = X[j].y;
            const float4 P0 = pk[j * 3 + 0];
            const float4 P1 = pk[j * 3 + 1];
            const float4 P2 = pk[j * 3 + 2];
            // three independent chains (nb = 0,1,2)
            float cn0 = __builtin_amdgcn_rcpf(__builtin_fmaf(E1, P0.y, 1.f));
            float cn1 = __builtin_amdgcn_rcpf(__builtin_fmaf(E1, P1.y, 1.f));
            float cn2 = __builtin_amdgcn_rcpf(__builtin_fmaf(E1, P2.y, 1.f));
            float sh0 = __builtin_fmaf(P0.x, __builtin_fmaf(-0.2f, cn0, 1.f), xv);
            float sh1 = __builtin_fmaf(P1.x, __builtin_fmaf(-0.2f, cn1, 1.f), xv);
            float sh2 = __builtin_fmaf(P2.x, __builtin_fmaf(-0.2f, cn2, 1.f), xv);
            float e20 = __builtin_amdgcn_exp2f(P0.z * sh0);
            float e21 = __builtin_amdgcn_exp2f(P1.z * sh1);
            float e22 = __builtin_amdgcn_exp2f(P2.z * sh2);
            float r0 = __builtin_amdgcn_rcpf(1.f + e20);
            float r1 = __builtin_amdgcn_rcpf(1.f + e21);
            float r2 = __builtin_amdgcn_rcpf(1.f + e22);
            a0 = __builtin_fmaf(-P0.w, r0, a0);
            a1 = __builtin_fmaf(-P1.w, r1, a1);
            a2 = __builtin_fmaf(-P2.w, r2, a2);
        }
    }
    red[tid] = a0 + a1 + a2;
    __syncthreads();
    if (tid < 64) {
        float r = red[tid] + red[tid + 64] + red[tid + 128] + red[tid + 192];
        int o = ((b * 32 + co) << 10) + (chunk << 6) + tid;
        out[o] = r + K0[co];
    }
}

extern "C" void kernel_launch(void* const* d_in, const int* in_sizes, int n_in,
                              void* d_out, int out_size, void* d_ws, size_t ws_size,
                              hipStream_t stream) {
    const float* x        = (const float*)d_in[0];
    const float* k        = (const float*)d_in[1];
    const float* Ec       = (const float*)d_in[2];
    const float* Ps       = (const float*)d_in[3];
    const float* bias     = (const float*)d_in[4];
    const float* coef     = (const float*)d_in[5];
    const float* out_bias = (const float*)d_in[6];
    float* out = (float*)d_out;

    float2* xe = (float2*)d_ws;
    float4* dp = (float4*)((char*)d_ws + 73984u * sizeof(float2));
    float*  K0 = (float*)((char*)d_ws + 73984u * sizeof(float2) + 13824u * sizeof(float4));

    prep_kernel<<<351, 256, 0, stream>>>(x, k, Ec, Ps, bias, coef, out_bias, xe, dp, K0);
    main_kernel<<<2048, 256, 0, stream>>>(xe, dp, K0, out);
}

// Round 4
// 30.650 us; speedup vs baseline: 1.5651x; 1.0364x over previous
//
#include <hip/hip_runtime.h>

#define LOG2E 1.4426950408889634f
#define C1 (10.0f * LOG2E)

// ws layout: xe (73984 float2) | dp (13824 float4) | K0 (32 f)
// xe = padded (x, E1=exp2(C1*x)) table, [b*16+ci][34][34], pad -> (0, 1).
// dp layout [co][ci][j=kh*3+kw][nb]: {T1=exp2(C1*Ec), Zk=2*LOG2E*k, ZkEc=Zk*Ec, W2=2*Ps*coef}
__global__ __launch_bounds__(256) void prep_kernel(
    const float* __restrict__ x,
    const float* __restrict__ kk, const float* __restrict__ Ec,
    const float* __restrict__ Ps, const float* __restrict__ bias,
    const float* __restrict__ coef, const float* __restrict__ out_bias,
    float2* __restrict__ xe, float4* __restrict__ dp, float* __restrict__ K0) {
    const int bid = blockIdx.x, tid = threadIdx.x;
    if (bid < 289) {                       // 289*256 = 73984 = 64*34*34
        int i = bid * 256 + tid;
        int ch = i / 1156;
        int rem = i - ch * 1156;
        int r = rem / 34;
        int c = rem - r * 34;
        float xv = 0.f;
        if ((unsigned)(r - 1) < 32u && (unsigned)(c - 1) < 32u)
            xv = x[(ch << 10) + (r - 1) * 32 + (c - 1)];
        xe[i] = make_float2(xv, __builtin_amdgcn_exp2f(C1 * xv));
    } else if (bid < 343) {                // 54*256 = 13824 params
        int i = (bid - 289) * 256 + tid;
        int co = i / 432;
        int r  = i - co * 432;             // input layout [ci][nb][j]
        int ci = r / 27;
        int r2 = r - ci * 27;
        int nb = r2 / 9;
        int j  = r2 - nb * 9;
        int o  = ((co * 16 + ci) * 9 + j) * 3 + nb;
        float e  = Ec[i];
        float zk = 2.0f * LOG2E * kk[i];
        dp[o] = make_float4(__builtin_amdgcn_exp2f(C1 * e), zk, zk * e,
                            2.0f * Ps[i] * coef[i]);
    } else {                               // 8 blocks x 4 waves: K0 per co
        int co = (bid - 343) * 4 + (tid >> 6);
        int lane = tid & 63;
        float sum = 0.f;
        for (int j = lane; j < 432; j += 64) {
            int idx = co * 432 + j;
            sum += coef[idx] * (Ps[idx] + bias[idx]);
        }
        #pragma unroll
        for (int off = 32; off >= 1; off >>= 1) sum += __shfl_down(sum, off, 64);
        if (lane == 0) K0[co] = sum + out_bias[co];
    }
}

// grid 2048 = (b:4, co:32, chunk:16 of 2 rows); 4 waves, wave w owns ci [4w,4w+4)
// __launch_bounds__(256, 8): 8 waves/EU => 8 blocks/CU, VGPR budget 64.
__global__ __launch_bounds__(256, 8) void main_kernel(
    const float2* __restrict__ xe, const float4* __restrict__ dp,
    const float* __restrict__ K0, float* __restrict__ out) {
    __shared__ float red[256];
    const int bid = blockIdx.x, tid = threadIdx.x;
    const int chunk = bid & 15;
    const int co    = (bid >> 4) & 31;
    const int b     = bid >> 9;
    const int px = tid & 63;
    const int w  = px & 31;
    const int h  = chunk * 2 + (px >> 5);
    const int cb = __builtin_amdgcn_readfirstlane((int)(tid >> 6)) * 4;

    // per-lane base into xe for ci = cb (advance by 1156 per ci)
    const float2* xp = xe + ((b * 16 + cb) * 34 + h + 1) * 34 + (w + 1);
    const float4* pk = dp + (co * 16 + cb) * 27;

    float a0 = 0.f, a1 = 0.f, a2 = 0.f;
    float2 X[9], Xn[9];
    #pragma unroll
    for (int j = 0; j < 9; ++j)
        X[j] = xp[(j / 3 - 1) * 34 + (j % 3 - 1)];

    #pragma unroll
    for (int i = 0; i < 4; ++i) {
        // prefetch next ci's window while computing this one
        if (i < 3) {
            const float2* xn = xp + (i + 1) * 1156;
            #pragma unroll
            for (int j = 0; j < 9; ++j)
                Xn[j] = xn[(j / 3 - 1) * 34 + (j % 3 - 1)];
        }
        const float4* pc = pk + i * 27;
        #pragma unroll
        for (int j = 0; j < 9; ++j) {
            const float xv = X[j].x, E1 = X[j].y;
            const float4 P0 = pc[j * 3 + 0];
            const float4 P1 = pc[j * 3 + 1];
            const float4 P2 = pc[j * 3 + 2];
            float cn0 = __builtin_amdgcn_rcpf(__builtin_fmaf(E1, P0.x, 1.f));
            float cn1 = __builtin_amdgcn_rcpf(__builtin_fmaf(E1, P1.x, 1.f));
            float cn2 = __builtin_amdgcn_rcpf(__builtin_fmaf(E1, P2.x, 1.f));
            float g0 = __builtin_fmaf(-0.2f, cn0, 1.f);
            float g1 = __builtin_fmaf(-0.2f, cn1, 1.f);
            float g2 = __builtin_fmaf(-0.2f, cn2, 1.f);
            float u0 = __builtin_fmaf(P0.y, xv, P0.z * g0);
            float u1 = __builtin_fmaf(P1.y, xv, P1.z * g1);
            float u2 = __builtin_fmaf(P2.y, xv, P2.z * g2);
            float e0 = __builtin_amdgcn_exp2f(u0);
            float e1 = __builtin_amdgcn_exp2f(u1);
            float e2 = __builtin_amdgcn_exp2f(u2);
            float r0 = __builtin_amdgcn_rcpf(1.f + e0);
            float r1 = __builtin_amdgcn_rcpf(1.f + e1);
            float r2 = __builtin_amdgcn_rcpf(1.f + e2);
            a0 = __builtin_fmaf(-P0.w, r0, a0);
            a1 = __builtin_fmaf(-P1.w, r1, a1);
            a2 = __builtin_fmaf(-P2.w, r2, a2);
        }
        #pragma unroll
        for (int j = 0; j < 9; ++j) X[j] = Xn[j];
    }
    red[tid] = a0 + a1 + a2;
    __syncthreads();
    if (tid < 64) {
        float r = red[tid] + red[tid + 64] + red[tid + 128] + red[tid + 192];
        int o = ((b * 32 + co) << 10) + (chunk << 6) + tid;
        out[o] = r + K0[co];
    }
}

extern "C" void kernel_launch(void* const* d_in, const int* in_sizes, int n_in,
                              void* d_out, int out_size, void* d_ws, size_t ws_size,
                              hipStream_t stream) {
    const float* x        = (const float*)d_in[0];
    const float* k        = (const float*)d_in[1];
    const float* Ec       = (const float*)d_in[2];
    const float* Ps       = (const float*)d_in[3];
    const float* bias     = (const float*)d_in[4];
    const float* coef     = (const float*)d_in[5];
    const float* out_bias = (const float*)d_in[6];
    float* out = (float*)d_out;

    float2* xe = (float2*)d_ws;
    float4* dp = (float4*)((char*)d_ws + 73984u * sizeof(float2));
    float*  K0 = (float*)((char*)d_ws + 73984u * sizeof(float2) + 13824u * sizeof(float4));

    prep_kernel<<<351, 256, 0, stream>>>(x, k, Ec, Ps, bias, coef, out_bias, xe, dp, K0);
    main_kernel<<<2048, 256, 0, stream>>>(xe, dp, K0, out);
}

// Round 5
// 30.640 us; speedup vs baseline: 1.5657x; 1.0003x over previous
//
#include <hip/hip_runtime.h>

#define LOG2E 1.4426950408889634f
#define C1 (10.0f * LOG2E)

// ws layout (bytes):
//   xe [73984 float2]  @ 0        : padded (x, E1=exp2(C1*x)), [b*16+ci][34][34], pad -> (0,1)
//   P4 [13824 float4]  @ 591872   : per [co][ci][j][nb] {T1=exp2(C1*Ec), Zk=2*LOG2E*k, A=Zk*Ec, B=0.2*A}
//   W2 [13824 float ]  @ 813056   : 2*Ps*coef, same order
//   K0 [32 float]      @ 868352
__global__ __launch_bounds__(256) void prep_kernel(
    const float* __restrict__ x,
    const float* __restrict__ kk, const float* __restrict__ Ec,
    const float* __restrict__ Ps, const float* __restrict__ bias,
    const float* __restrict__ coef, const float* __restrict__ out_bias,
    float2* __restrict__ xe, float4* __restrict__ P4,
    float* __restrict__ W2, float* __restrict__ K0) {
    const int bid = blockIdx.x, tid = threadIdx.x;
    if (bid < 289) {                       // 289*256 = 73984 = 64*34*34
        int i = bid * 256 + tid;
        int ch = i / 1156;
        int rem = i - ch * 1156;
        int r = rem / 34;
        int c = rem - r * 34;
        float xv = 0.f;
        if ((unsigned)(r - 1) < 32u && (unsigned)(c - 1) < 32u)
            xv = x[(ch << 10) + (r - 1) * 32 + (c - 1)];
        xe[i] = make_float2(xv, __builtin_amdgcn_exp2f(C1 * xv));
    } else if (bid < 343) {                // 54*256 = 13824 params
        int i = (bid - 289) * 256 + tid;
        int co = i / 432;
        int r  = i - co * 432;             // input layout [ci][nb][j]
        int ci = r / 27;
        int r2 = r - ci * 27;
        int nb = r2 / 9;
        int j  = r2 - nb * 9;
        int o  = ((co * 16 + ci) * 9 + j) * 3 + nb;
        float e  = Ec[i];
        float zk = 2.0f * LOG2E * kk[i];
        float a  = zk * e;
        P4[o] = make_float4(__builtin_amdgcn_exp2f(C1 * e), zk, a, 0.2f * a);
        W2[o] = 2.0f * Ps[i] * coef[i];
    } else {                               // 8 blocks x 4 waves: K0 per co
        int co = (bid - 343) * 4 + (tid >> 6);
        int lane = tid & 63;
        float sum = 0.f;
        for (int j = lane; j < 432; j += 64) {
            int idx = co * 432 + j;
            sum += coef[idx] * (Ps[idx] + bias[idx]);
        }
        #pragma unroll
        for (int off = 32; off >= 1; off >>= 1) sum += __shfl_down(sum, off, 64);
        if (lane == 0) K0[co] = sum + out_bias[co];
    }
}

// grid 2048 = (b:4, co:32, chunk:16 of 2 rows); 4 waves; wave w owns ci [4w,4w+4).
// Params staged in LDS (broadcast reads, imm offsets). launch_bounds(256,6): VGPR<=85.
__global__ __launch_bounds__(256, 6) void main_kernel(
    const float2* __restrict__ xe, const float4* __restrict__ P4,
    const float* __restrict__ W2, const float* __restrict__ K0,
    float* __restrict__ out) {
    __shared__ float4 sP[432];
    __shared__ float  sW[432];
    __shared__ float  red[256];
    const int bid = blockIdx.x, tid = threadIdx.x;
    const int chunk = bid & 15;
    const int co    = (bid >> 4) & 31;
    const int b     = bid >> 9;
    const int px = tid & 63;
    const int w  = px & 31;
    const int h  = chunk * 2 + (px >> 5);
    const int cb = (tid >> 6) << 2;

    // stage this co's params into LDS
    #pragma unroll
    for (int i = tid; i < 432; i += 256) {
        sP[i] = P4[co * 432 + i];
        sW[i] = W2[co * 432 + i];
    }

    const float2* xp = xe + ((b * 16 + cb) * 34 + h + 1) * 34 + (w + 1);

    float2 X[9], Xn[9];
    #pragma unroll
    for (int j = 0; j < 9; ++j)
        X[j] = xp[(j / 3 - 1) * 34 + (j % 3 - 1)];

    __syncthreads();

    float a0 = 0.f, a1 = 0.f, a2 = 0.f;
    #pragma unroll
    for (int i = 0; i < 4; ++i) {
        if (i < 3) {
            const float2* xn = xp + (i + 1) * 1156;
            #pragma unroll
            for (int j = 0; j < 9; ++j)
                Xn[j] = xn[(j / 3 - 1) * 34 + (j % 3 - 1)];
        }
        const float4* pc = &sP[(cb + i) * 27];
        const float*  wc = &sW[(cb + i) * 27];
        #pragma unroll
        for (int j = 0; j < 9; ++j) {
            const float xv = X[j].x, E1 = X[j].y;
            const float4 P0 = pc[j * 3 + 0];
            const float4 P1 = pc[j * 3 + 1];
            const float4 P2 = pc[j * 3 + 2];
            const float w0 = wc[j * 3 + 0];
            const float w1 = wc[j * 3 + 1];
            const float w2 = wc[j * 3 + 2];
            float cn0 = __builtin_amdgcn_rcpf(__builtin_fmaf(E1, P0.x, 1.f));
            float cn1 = __builtin_amdgcn_rcpf(__builtin_fmaf(E1, P1.x, 1.f));
            float cn2 = __builtin_amdgcn_rcpf(__builtin_fmaf(E1, P2.x, 1.f));
            float t0 = __builtin_fmaf(P0.y, xv, P0.z);
            float t1 = __builtin_fmaf(P1.y, xv, P1.z);
            float t2 = __builtin_fmaf(P2.y, xv, P2.z);
            float u0 = __builtin_fmaf(-P0.w, cn0, t0);
            float u1 = __builtin_fmaf(-P1.w, cn1, t1);
            float u2 = __builtin_fmaf(-P2.w, cn2, t2);
            float e0 = __builtin_amdgcn_exp2f(u0);
            float e1 = __builtin_amdgcn_exp2f(u1);
            float e2 = __builtin_amdgcn_exp2f(u2);
            float r0 = __builtin_amdgcn_rcpf(1.f + e0);
            float r1 = __builtin_amdgcn_rcpf(1.f + e1);
            float r2 = __builtin_amdgcn_rcpf(1.f + e2);
            a0 = __builtin_fmaf(-w0, r0, a0);
            a1 = __builtin_fmaf(-w1, r1, a1);
            a2 = __builtin_fmaf(-w2, r2, a2);
        }
        #pragma unroll
        for (int j = 0; j < 9; ++j) X[j] = Xn[j];
    }
    red[tid] = a0 + a1 + a2;
    __syncthreads();
    if (tid < 64) {
        float r = red[tid] + red[tid + 64] + red[tid + 128] + red[tid + 192];
        int o = ((b * 32 + co) << 10) + (chunk << 6) + tid;
        out[o] = r + K0[co];
    }
}

extern "C" void kernel_launch(void* const* d_in, const int* in_sizes, int n_in,
                              void* d_out, int out_size, void* d_ws, size_t ws_size,
                              hipStream_t stream) {
    const float* x        = (const float*)d_in[0];
    const float* k        = (const float*)d_in[1];
    const float* Ec       = (const float*)d_in[2];
    const float* Ps       = (const float*)d_in[3];
    const float* bias     = (const float*)d_in[4];
    const float* coef     = (const float*)d_in[5];
    const float* out_bias = (const float*)d_in[6];
    float* out = (float*)d_out;

    float2* xe = (float2*)d_ws;
    float4* P4 = (float4*)((char*)d_ws + 591872u);
    float*  W2 = (float*)((char*)d_ws + 813056u);
    float*  K0 = (float*)((char*)d_ws + 868352u);

    prep_kernel<<<351, 256, 0, stream>>>(x, k, Ec, Ps, bias, coef, out_bias, xe, P4, W2, K0);
    main_kernel<<<2048, 256, 0, stream>>>(xe, P4, W2, K0, out);
}